// Round 3
// baseline (433.819 us; speedup 1.0000x reference)
//
#include <hip/hip_runtime.h>

// ---- sizes ----
// x: (1024,1,28,28); h1: (1024,32,14,14); h2: (1024,64,14,14)->12544; out: (1024,10)
#define NB 1024
#define TOTAL1 (NB*196)

// ws layout (float offsets)
#define WS_H1   0               // 1024*32*196      = 6422528
#define WS_H2   6422528         // 1024*12544      = 12845056
#define WS_PART 19267584        // 32*1024*128     = 4194304
#define WS_W1T  23461888        // 288
#define WS_OW1T 23462176        // 162
#define WS_W2T  23462338        // 18432  [k=ci*9+kk][co=64]
#define WS_OW2T 23480770        // 5184   [k=ci*9+j][c=18]

// ---------------- weight transpose prep ----------------
__global__ __launch_bounds__(256) void prep(const float* __restrict__ w1,
                                            const float* __restrict__ ow1,
                                            const float* __restrict__ w2,
                                            const float* __restrict__ ow2,
                                            float* __restrict__ ws) {
  int i = blockIdx.x * 256 + threadIdx.x;
  if (i < 288)   { int co = i / 9,  kk = i % 9;   ws[WS_W1T  + kk * 32 + co] = w1[i]; }
  if (i < 162)   { int c  = i / 9,  j  = i % 9;   ws[WS_OW1T + j  * 18 + c ] = ow1[i]; }
  if (i < 18432) { int co = i / 288, k = i % 288; ws[WS_W2T  + k  * 64 + co] = w2[i]; }
  if (i < 5184)  { int c  = i / 288, k = i % 288; ws[WS_OW2T + k  * 18 + c ] = ow2[i]; }
}

// ---------------- stage 1: offset conv + deform conv (1->32) + relu + pool 28->14 ----------------
__global__ __launch_bounds__(256, 2) void stage1(const float* __restrict__ x,
                                                 const float* __restrict__ ob1,
                                                 const float* __restrict__ b1,
                                                 const float* __restrict__ ws,
                                                 float* __restrict__ h1) {
  __shared__ float ximg[3 * 784];
  const float* __restrict__ w1t  = ws + WS_W1T;   // [kk][32]
  const float* __restrict__ ow1t = ws + WS_OW1T;  // [j][18]
  int tid = threadIdx.x;
  int g0 = blockIdx.x * 256;
  int bfirst = g0 / 196;
  for (int idx = tid; idx < 3 * 784; idx += 256) {
    int img = idx / 784;
    int b = bfirst + img;
    ximg[idx] = (b < NB) ? x[b * 784 + (idx - img * 784)] : 0.f;
  }
  __syncthreads();
  int g = g0 + tid;
  if (g >= TOTAL1) return;
  int b = g / 196, p = g - b * 196;
  const float* im = ximg + (b - bfirst) * 784;
  int oy = p / 14, ox = p - (p / 14) * 14;

  float pooled[32];
#pragma unroll
  for (int co = 0; co < 32; ++co) pooled[co] = 0.f;

  for (int sub = 0; sub < 4; ++sub) {
    int y  = 2 * oy + (sub >> 1);
    int ix = 2 * ox + (sub & 1);
    float patch[9];
#pragma unroll
    for (int j = 0; j < 9; ++j) {
      int yy = y + j / 3 - 1, xc = ix + j % 3 - 1;
      bool ok = (yy >= 0) & (yy < 28) & (xc >= 0) & (xc < 28);
      patch[j] = ok ? im[yy * 28 + xc] : 0.f;
    }
    float off[18];
#pragma unroll
    for (int c = 0; c < 18; ++c) off[c] = ob1[c];
#pragma unroll
    for (int j = 0; j < 9; ++j) {
      float v = patch[j];
#pragma unroll
      for (int c = 0; c < 18; ++c) off[c] = fmaf(v, ow1t[j * 18 + c], off[c]);
    }
    float a[32];
#pragma unroll
    for (int co = 0; co < 32; ++co) a[co] = b1[co];
#pragma unroll
    for (int kk = 0; kk < 9; ++kk) {
      float py = (float)(y - 1 + kk / 3) + off[2 * kk];
      float px = (float)(ix - 1 + kk % 3) + off[2 * kk + 1];
      float y0f = floorf(py), x0f = floorf(px);
      float wy1 = py - y0f, wx1 = px - x0f;
      float wy0 = 1.f - wy1, wx0 = 1.f - wx1;
      int y0 = (int)y0f, x0 = (int)x0f;
      int y1 = y0 + 1, x1 = x0 + 1;
      bool vy0 = (y0 >= 0) & (y0 < 28), vy1 = (y1 >= 0) & (y1 < 28);
      bool vx0 = (x0 >= 0) & (x0 < 28), vx1 = (x1 >= 0) & (x1 < 28);
      float W00 = (vy0 & vx0) ? wy0 * wx0 : 0.f;
      float W01 = (vy0 & vx1) ? wy0 * wx1 : 0.f;
      float W10 = (vy1 & vx0) ? wy1 * wx0 : 0.f;
      float W11 = (vy1 & vx1) ? wy1 * wx1 : 0.f;
      int yc0 = min(max(y0, 0), 27), yc1 = min(max(y1, 0), 27);
      int xc0 = min(max(x0, 0), 27), xc1 = min(max(x1, 0), 27);
      float s = im[yc0 * 28 + xc0] * W00 + im[yc0 * 28 + xc1] * W01 +
                im[yc1 * 28 + xc0] * W10 + im[yc1 * 28 + xc1] * W11;
#pragma unroll
      for (int co = 0; co < 32; ++co) a[co] = fmaf(s, w1t[kk * 32 + co], a[co]);
    }
#pragma unroll
    for (int co = 0; co < 32; ++co) pooled[co] += fmaxf(a[co], 0.f);
  }
#pragma unroll
  for (int co = 0; co < 32; ++co) h1[b * 6272 + co * 196 + p] = pooled[co] * 0.25f;
}

// ---------------- stage 2 v7: thread-per-pixel, acc[64], SMEM weights, no Sbuf ----------------
// Block = 448 threads = 2 images x 224 pixel-slots (14x16 grid; cols 14,15 duplicate col 13).
// LDS: imgT only, 2*6272*4 = 50176B. One barrier total. Offset conv fused in-register.
// All weight reads are wave-uniform (loop indices only) -> scalar K$ loads, no LDS/VMEM.
__global__ __launch_bounds__(448, 4) void stage2(const float* __restrict__ h1,
                                                 const float* __restrict__ ob2,
                                                 const float* __restrict__ b2,
                                                 const float* __restrict__ ws,
                                                 float* __restrict__ h2) {
  __shared__ float imgT[2 * 6272];       // imgT[img][p*32 + ((ci+4p)&31)] = img[ci][p]
  const float* __restrict__ w2t  = ws + WS_W2T;   // [ci*9+kk][64]
  const float* __restrict__ ow2t = ws + WS_OW2T;  // [ci*9+j][18]
  int tid = threadIdx.x;
  int bb = blockIdx.x;  // 0..511, images 2bb, 2bb+1

  // ---- phase A: cooperative load of both images, transposed + bank-rotated ----
  for (int e = tid; e < 12544; e += 448) {
    int img = e / 6272, rem = e - img * 6272;
    int ci = rem / 196, p = rem - ci * 196;
    imgT[img * 6272 + p * 32 + ((ci + 4 * p) & 31)] = h1[bb * 12544 + e];
  }
  __syncthreads();  // the only barrier

  int img  = tid / 224;
  int slot = tid - img * 224;
  int py  = slot >> 4;        // 0..13
  int pxc = slot & 15;        // 0..15 (14,15 = pad)
  int pxx = min(pxc, 13);     // pad threads duplicate col 13 (valid-by-construction)
  int p   = py * 14 + pxx;
  const float* im = imgT + img * 6272;

  // ---- offset conv (32->18) fully in-register ----
  float off[18];
#pragma unroll
  for (int c = 0; c < 18; ++c) off[c] = ob2[c];
  for (int j = 0; j < 9; ++j) {
    int yy = py + j / 3 - 1, xx = pxx + j % 3 - 1;
    bool ok = (yy >= 0) & (yy < 14) & (xx >= 0) & (xx < 14);
    int nidx = ok ? (yy * 14 + xx) : 0;
    const float* src = im + nidx * 32;
    int rot = (4 * nidx) & 31;
    for (int cq = 0; cq < 8; ++cq) {
      float4 v;
      if (ok) v = *(const float4*)(src + ((cq * 4 + rot) & 31));
      else    v = make_float4(0.f, 0.f, 0.f, 0.f);
      const float* w0 = ow2t + ((cq * 4 + 0) * 9 + j) * 18;
      const float* w1 = ow2t + ((cq * 4 + 1) * 9 + j) * 18;
      const float* w2 = ow2t + ((cq * 4 + 2) * 9 + j) * 18;
      const float* w3 = ow2t + ((cq * 4 + 3) * 9 + j) * 18;
#pragma unroll
      for (int c = 0; c < 18; ++c) {
        off[c] = fmaf(v.x, w0[c], off[c]);
        off[c] = fmaf(v.y, w1[c], off[c]);
        off[c] = fmaf(v.z, w2[c], off[c]);
        off[c] = fmaf(v.w, w3[c], off[c]);
      }
    }
  }

  // ---- deformable conv (32->64), acc[64] in VGPRs ----
  float acc[64];
#pragma unroll
  for (int co = 0; co < 64; ++co) acc[co] = b2[co];

  for (int kk = 0; kk < 9; ++kk) {
    // extract this tap's (dy,dx) without runtime VGPR indexing
    float dy = off[0], dx = off[1];
#pragma unroll
    for (int t = 1; t < 9; ++t) if (kk == t) { dy = off[2 * t]; dx = off[2 * t + 1]; }

    float pyv = (float)(py - 1 + kk / 3) + dy;
    float pxv = (float)(pxx - 1 + kk % 3) + dx;
    float y0f = floorf(pyv), x0f = floorf(pxv);
    float wy1 = pyv - y0f, wx1 = pxv - x0f;
    float wy0 = 1.f - wy1, wx0 = 1.f - wx1;
    int y0 = (int)y0f, x0 = (int)x0f;
    int y1 = y0 + 1, x1 = x0 + 1;
    bool vy0 = (y0 >= 0) & (y0 < 14), vy1 = (y1 >= 0) & (y1 < 14);
    bool vx0 = (x0 >= 0) & (x0 < 14), vx1 = (x1 >= 0) & (x1 < 14);
    float W00 = (vy0 & vx0) ? wy0 * wx0 : 0.f;
    float W01 = (vy0 & vx1) ? wy0 * wx1 : 0.f;
    float W10 = (vy1 & vx0) ? wy1 * wx0 : 0.f;
    float W11 = (vy1 & vx1) ? wy1 * wx1 : 0.f;
    int yc0 = min(max(y0, 0), 13), yc1 = min(max(y1, 0), 13);
    int xc0 = min(max(x0, 0), 13), xc1 = min(max(x1, 0), 13);
    int i00 = yc0 * 14 + xc0, i01 = yc0 * 14 + xc1;
    int i10 = yc1 * 14 + xc0, i11 = yc1 * 14 + xc1;
    int o00 = i00 * 32, r00 = (4 * i00) & 31;
    int o01 = i01 * 32, r01 = (4 * i01) & 31;
    int o10 = i10 * 32, r10 = (4 * i10) & 31;
    int o11 = i11 * 32, r11 = (4 * i11) & 31;

    for (int cq = 0; cq < 8; ++cq) {
      float4 a0 = *(const float4*)(im + o00 + ((cq * 4 + r00) & 31));
      float4 a1 = *(const float4*)(im + o01 + ((cq * 4 + r01) & 31));
      float4 a2 = *(const float4*)(im + o10 + ((cq * 4 + r10) & 31));
      float4 a3 = *(const float4*)(im + o11 + ((cq * 4 + r11) & 31));
      float s0 = fmaf(W00, a0.x, fmaf(W01, a1.x, fmaf(W10, a2.x, W11 * a3.x)));
      float s1 = fmaf(W00, a0.y, fmaf(W01, a1.y, fmaf(W10, a2.y, W11 * a3.y)));
      float s2 = fmaf(W00, a0.z, fmaf(W01, a1.z, fmaf(W10, a2.z, W11 * a3.z)));
      float s3 = fmaf(W00, a0.w, fmaf(W01, a1.w, fmaf(W10, a2.w, W11 * a3.w)));
#pragma unroll
      for (int u = 0; u < 4; ++u) {
        float su = (u == 0) ? s0 : (u == 1) ? s1 : (u == 2) ? s2 : s3;
        const float* wr = w2t + ((cq * 4 + u) * 9 + kk) * 64;  // wave-uniform -> s_load
#pragma unroll
        for (int co = 0; co < 64; ++co)
          acc[co] = fmaf(su, wr[co], acc[co]);
      }
    }
  }

  // ---- ReLU + store (coalesced across lanes; pad threads skip) ----
  if (pxc < 14) {
    int base = (2 * bb + img) * 12544 + p;
#pragma unroll
    for (int co = 0; co < 64; ++co)
      h2[base + co * 196] = fmaxf(acc[co], 0.f);
  }
}

// ---------------- fc1: K-split GEMM 1024x128, K=12544 -> partials[32][1024][128] ----------------
__global__ __launch_bounds__(256, 2) void fc1(const float* __restrict__ h2,
                                              const float* __restrict__ fw1,
                                              float* __restrict__ part) {
  __shared__ float a_s[56 * 72];   // [k][r]
  __shared__ float b_s[56 * 132];  // [k][c]
  int tid = threadIdx.x;
  int rb = (blockIdx.x & 15) * 64;
  int ks = blockIdx.x >> 4;
  int kbase = ks * 392;
  int c0 = (tid & 31) * 4;
  int r0 = (tid >> 5) * 8;

  float acc[8][4];
#pragma unroll
  for (int i = 0; i < 8; ++i)
#pragma unroll
    for (int j = 0; j < 4; ++j) acc[i][j] = 0.f;

  for (int ch = 0; ch < 7; ++ch) {
    int kb = kbase + ch * 56;
    __syncthreads();
#pragma unroll
    for (int t = 0; t < 14; ++t) {
      int idx = t * 256 + tid;
      int r = idx / 56, k = idx - r * 56;
      a_s[k * 72 + r] = h2[(rb + r) * 12544 + kb + k];
    }
#pragma unroll
    for (int t = 0; t < 28; ++t) {
      int idx = t * 256 + tid;
      int c = idx / 56, k = idx - c * 56;
      b_s[k * 132 + c] = fw1[c * 12544 + kb + k];
    }
    __syncthreads();
    for (int k = 0; k < 56; ++k) {
      float4 bv = *(const float4*)&b_s[k * 132 + c0];
      float4 av0 = *(const float4*)&a_s[k * 72 + r0];
      float4 av1 = *(const float4*)&a_s[k * 72 + r0 + 4];
      float av[8] = {av0.x, av0.y, av0.z, av0.w, av1.x, av1.y, av1.z, av1.w};
      float bj[4] = {bv.x, bv.y, bv.z, bv.w};
#pragma unroll
      for (int i = 0; i < 8; ++i)
#pragma unroll
        for (int j = 0; j < 4; ++j) acc[i][j] = fmaf(av[i], bj[j], acc[i][j]);
    }
  }
#pragma unroll
  for (int i = 0; i < 8; ++i) {
    int r = rb + r0 + i;
#pragma unroll
    for (int j = 0; j < 4; ++j)
      part[(ks * 1024 + r) * 128 + c0 + j] = acc[i][j];
  }
}

// ---------------- reduce partials + bias + relu + fc2 ----------------
__global__ __launch_bounds__(128) void fcfinal(const float* __restrict__ part,
                                               const float* __restrict__ fb1,
                                               const float* __restrict__ fw2,
                                               const float* __restrict__ fb2,
                                               float* __restrict__ out) {
  __shared__ float tbuf[128];
  int b = blockIdx.x, c = threadIdx.x;
  float s = fb1[c];
  for (int ks = 0; ks < 32; ++ks) s += part[(ks * 1024 + b) * 128 + c];
  tbuf[c] = fmaxf(s, 0.f);
  __syncthreads();
  if (c < 10) {
    float v = fb2[c];
#pragma unroll
    for (int k = 0; k < 128; ++k) v = fmaf(tbuf[k], fw2[c * 128 + k], v);
    out[b * 10 + c] = v;
  }
}

extern "C" void kernel_launch(void* const* d_in, const int* in_sizes, int n_in,
                              void* d_out, int out_size, void* d_ws, size_t ws_size,
                              hipStream_t stream) {
  const float* x   = (const float*)d_in[0];
  const float* ow1 = (const float*)d_in[1];
  const float* ob1 = (const float*)d_in[2];
  const float* w1  = (const float*)d_in[3];
  const float* b1  = (const float*)d_in[4];
  const float* ow2 = (const float*)d_in[5];
  const float* ob2 = (const float*)d_in[6];
  const float* w2  = (const float*)d_in[7];
  const float* b2  = (const float*)d_in[8];
  const float* fw1 = (const float*)d_in[9];
  const float* fb1 = (const float*)d_in[10];
  const float* fw2 = (const float*)d_in[11];
  const float* fb2 = (const float*)d_in[12];
  float* ws  = (float*)d_ws;
  float* out = (float*)d_out;

  prep<<<72, 256, 0, stream>>>(w1, ow1, w2, ow2, ws);
  stage1<<<784, 256, 0, stream>>>(x, ob1, b1, ws, ws + WS_H1);
  stage2<<<512, 448, 0, stream>>>(ws + WS_H1, ob2, b2, ws, ws + WS_H2);
  fc1<<<512, 256, 0, stream>>>(ws + WS_H2, fw1, ws + WS_PART);
  fcfinal<<<1024, 128, 0, stream>>>(ws + WS_PART, fb1, fw2, fb2, out);
}